// Round 3
// baseline (1151.813 us; speedup 1.0000x reference)
//
#include <hip/hip_runtime.h>
#include <stdint.h>

typedef float f2 __attribute__((ext_vector_type(2)));
typedef float f4 __attribute__((ext_vector_type(4)));

// res[l] = floor(16 * b^l), b = exp((ln512 - ln16)/15) in fp32.
__constant__ float c_res[16] = {16.f, 20.f, 25.f, 32.f, 40.f, 50.f, 64.f, 80.f,
                                101.f, 128.f, 161.f, 203.f, 256.f, 322.f, 406.f, 512.f};

#define HASH_MASK ((1u << 19) - 1u)
#define P1 2654435761u
#define P2 805459861u
#define PTS_PER_THREAD 4
#define NBINS 32768   // 15-bit Morton code at res 32

// ---- Morton bucketing -------------------------------------------------------
__device__ __forceinline__ uint32_t spread5(uint32_t v) {
    // 5 bits -> positions 0,3,6,9,12
    return (v & 1u) | ((v & 2u) << 2) | ((v & 4u) << 4) |
           ((v & 8u) << 6) | ((v & 16u) << 8);
}

__device__ __forceinline__ uint32_t bucket_of(float x0, float x1, float x2) {
    x0 = fminf(fmaxf(x0, 0.f), 1.f);
    x1 = fminf(fmaxf(x1, 0.f), 1.f);
    x2 = fminf(fmaxf(x2, 0.f), 1.f);
    uint32_t cx = (uint32_t)(x0 * 32.f); cx = cx > 31u ? 31u : cx;
    uint32_t cy = (uint32_t)(x1 * 32.f); cy = cy > 31u ? 31u : cy;
    uint32_t cz = (uint32_t)(x2 * 32.f); cz = cz > 31u ? 31u : cz;
    return spread5(cx) | (spread5(cy) << 1) | (spread5(cz) << 2);
}

__global__ void hist_kernel(const float* __restrict__ x, uint32_t* __restrict__ hist,
                            int n) {
    int p = blockIdx.x * blockDim.x + threadIdx.x;
    int stride = gridDim.x * blockDim.x;
    for (; p < n; p += stride) {
        float x0 = x[3 * (size_t)p + 0];
        float x1 = x[3 * (size_t)p + 1];
        float x2 = x[3 * (size_t)p + 2];
        atomicAdd(&hist[bucket_of(x0, x1, x2)], 1u);
    }
}

// One block, 256 threads, exclusive scan of 32768 bins.
__global__ void scan_kernel(const uint32_t* __restrict__ hist,
                            uint32_t* __restrict__ offs) {
    __shared__ uint32_t part[256];
    int t = threadIdx.x;
    uint32_t s = 0;
    #pragma unroll 8
    for (int i = 0; i < NBINS / 256; ++i) s += hist[t * (NBINS / 256) + i];
    part[t] = s;
    __syncthreads();
    for (int d = 1; d < 256; d <<= 1) {
        uint32_t a = (t >= d) ? part[t - d] : 0u;
        __syncthreads();
        part[t] += a;
        __syncthreads();
    }
    uint32_t base = (t == 0) ? 0u : part[t - 1];
    for (int i = 0; i < NBINS / 256; ++i) {
        int j = t * (NBINS / 256) + i;
        uint32_t h = hist[j];
        offs[j] = base;
        base += h;
    }
}

// Scatter points into Morton-sorted order. xs[pos] = (x0,x1,x2, bitcast(orig)).
__global__ void scatter_kernel(const float* __restrict__ x,
                               uint32_t* __restrict__ offs,
                               f4* __restrict__ xs, int n) {
    int p = blockIdx.x * blockDim.x + threadIdx.x;
    int stride = gridDim.x * blockDim.x;
    for (; p < n; p += stride) {
        float x0 = x[3 * (size_t)p + 0];
        float x1 = x[3 * (size_t)p + 1];
        float x2 = x[3 * (size_t)p + 2];
        uint32_t b = bucket_of(x0, x1, x2);
        uint32_t pos = atomicAdd(&offs[b], 1u);
        f4 v = {x0, x1, x2, __uint_as_float((uint32_t)p)};
        xs[pos] = v;
    }
}

// ---- Encode -----------------------------------------------------------------
// Grid: 2 phases (levels 0-7, 8-15) x chunks x 8 levels; blockIdx%8 == level%8
// pins each level's table to one XCD L2. SORTED path reads Morton-clustered
// points: a block's 1024 points span ~0.1^3 of the cube, so levels 0-8's
// table window fits (mostly) in the 32KB L1 -> gather becomes L1-hit instead
// of the serialized random-L2 path (measured wall: ~10 x 8B-beats/cy/XCD,
// invariant across request packaging in R1/R2).
template <bool SORTED>
__global__ __launch_bounds__(256, 4) void hash_encode_kernel(
    const float* __restrict__ x,
    const f4* __restrict__ xs,
    const float* __restrict__ tables,
    float* __restrict__ out,
    float* __restrict__ mask_out,
    int n_points,
    int blocks_per_phase)
{
    int bid = blockIdx.x;
    int level_base = 0;
    if (bid >= blocks_per_phase) { bid -= blocks_per_phase; level_base = 8; }
    int level = (bid & 7) + level_base;
    int chunk = bid >> 3;

    float res  = c_res[level];
    float grid = 1.0f / res;
    const f2* __restrict__ tab =
        (const f2*)tables + ((size_t)level << 19);   // 2^19 float2 per level
    const f4* __restrict__ tab4 = (const f4*)tab;    // 2^18 float4 per level

    int pbase = chunk * (256 * PTS_PER_THREAD) + threadIdx.x;

    uint32_t idx[PTS_PER_THREAD][8];
    float wx[PTS_PER_THREAD], wy[PTS_PER_THREAD], wz[PTS_PER_THREAD];
    bool valid[PTS_PER_THREAD];
    bool bxodd[PTS_PER_THREAD];
    uint32_t pp[PTS_PER_THREAD];

    #pragma unroll
    for (int s = 0; s < PTS_PER_THREAD; ++s) {
        int p = pbase + s * 256;
        valid[s] = (p < n_points);
        int pc = valid[s] ? p : 0;

        float x0, x1, x2;
        uint32_t op;
        if constexpr (SORTED) {
            f4 v = xs[pc];
            x0 = v.x; x1 = v.y; x2 = v.z;
            op = __float_as_uint(v.w);
        } else {
            x0 = __builtin_nontemporal_load(&x[3 * (size_t)pc + 0]);
            x1 = __builtin_nontemporal_load(&x[3 * (size_t)pc + 1]);
            x2 = __builtin_nontemporal_load(&x[3 * (size_t)pc + 2]);
            op = (uint32_t)pc;
        }
        pp[s] = op;

        if (level == 0 && valid[s]) {
            bool keep = (x0 >= 0.f) & (x0 <= 1.f) &
                        (x1 >= 0.f) & (x1 <= 1.f) &
                        (x2 >= 0.f) & (x2 <= 1.f);
            __builtin_nontemporal_store(keep ? 1.0f : 0.0f, &mask_out[op]);
        }

        x0 = fminf(fmaxf(x0, 0.f), 1.f);
        x1 = fminf(fmaxf(x1, 0.f), 1.f);
        x2 = fminf(fmaxf(x2, 0.f), 1.f);

        // Keep the exact fp32 sequence of the verified kernel (floor(x/grid)),
        // grid = 1/res: changing to x*res can flip buckets by 1 ulp.
        float b0 = floorf(x0 / grid);
        float b1 = floorf(x1 / grid);
        float b2 = floorf(x2 / grid);

        wx[s] = (x0 - b0 * grid) / grid;
        wy[s] = (x1 - b1 * grid) / grid;
        wz[s] = (x2 - b2 * grid) / grid;

        uint32_t bx = (uint32_t)b0;
        uint32_t by = (uint32_t)b1;
        uint32_t bz = (uint32_t)b2;

        bxodd[s] = (bx & 1u) != 0u;

        uint32_t hx0 = bx;        uint32_t hx1 = bx + 1u;
        uint32_t hy0 = by * P1;   uint32_t hy1 = hy0 + P1;
        uint32_t hz0 = bz * P2;   uint32_t hz1 = hz0 + P2;

        idx[s][0] = (hx0 ^ hy0 ^ hz0) & HASH_MASK;
        idx[s][1] = (hx0 ^ hy0 ^ hz1) & HASH_MASK;
        idx[s][2] = (hx0 ^ hy1 ^ hz0) & HASH_MASK;
        idx[s][3] = (hx0 ^ hy1 ^ hz1) & HASH_MASK;
        idx[s][4] = (hx1 ^ hy0 ^ hz0) & HASH_MASK;
        idx[s][5] = (hx1 ^ hy0 ^ hz1) & HASH_MASK;
        idx[s][6] = (hx1 ^ hy1 ^ hz0) & HASH_MASK;
        idx[s][7] = (hx1 ^ hy1 ^ hz1) & HASH_MASK;
    }

    // Issue all gathers before any consumption. Even-bx lanes: 4x16B paired
    // loads (idx[j] and idx[j]^1 == idx[j+4] share a float4). Odd-bx lanes:
    // 8x8B.
    f2 e[PTS_PER_THREAD][8];
    #pragma unroll
    for (int s = 0; s < PTS_PER_THREAD; ++s) {
        if (!bxodd[s]) {
            #pragma unroll
            for (int j = 0; j < 4; ++j) {
                uint32_t q = idx[s][j];
                f4 v = tab4[q >> 1];
                f2 lov = {v.x, v.y};
                f2 hiv = {v.z, v.w};
                bool hi = (q & 1u) != 0u;
                e[s][j]     = hi ? hiv : lov;   // entry q     (x = bx)
                e[s][j + 4] = hi ? lov : hiv;   // entry q ^ 1 (x = bx+1)
            }
        } else {
            #pragma unroll
            for (int c = 0; c < 8; ++c)
                e[s][c] = tab[idx[s][c]];
        }
    }

    #pragma unroll
    for (int s = 0; s < PTS_PER_THREAD; ++s) {
        float owx = 1.f - wx[s], owy = 1.f - wy[s], owz = 1.f - wz[s];

        f2 c00 = e[s][0] * owx + e[s][4] * wx[s];
        f2 c01 = e[s][1] * owx + e[s][5] * wx[s];
        f2 c10 = e[s][2] * owx + e[s][6] * wx[s];
        f2 c11 = e[s][3] * owx + e[s][7] * wx[s];

        f2 c0 = c00 * owy + c10 * wy[s];
        f2 c1 = c01 * owy + c11 * wy[s];

        f2 cv = c0 * owz + c1 * wz[s];

        if (valid[s]) {
            f2* dst = (f2*)(out + (size_t)pp[s] * 32) + level;
            __builtin_nontemporal_store(cv, dst);
        }
    }
}

extern "C" void kernel_launch(void* const* d_in, const int* in_sizes, int n_in,
                              void* d_out, int out_size, void* d_ws, size_t ws_size,
                              hipStream_t stream) {
    const float* x      = (const float*)d_in[0];
    const float* tables = (const float*)d_in[1];
    float* out = (float*)d_out;
    int n_points = in_sizes[0] / 3;
    float* mask_out = out + (size_t)n_points * 32;

    int chunks = (n_points + 256 * PTS_PER_THREAD - 1) / (256 * PTS_PER_THREAD);
    int blocks_per_phase = chunks * 8;
    int blocks = blocks_per_phase * 2;

    // ws layout: [0,128K) hist, [128K,256K) offsets, [256K, 256K+16*n) xs.
    size_t need = 262144 + (size_t)n_points * sizeof(f4);

    if (ws_size >= need && n_points > 0) {
        uint32_t* hist = (uint32_t*)d_ws;
        uint32_t* offs = hist + NBINS;
        f4* xs = (f4*)((char*)d_ws + 262144);

        hipMemsetAsync(hist, 0, NBINS * sizeof(uint32_t), stream);
        hipLaunchKernelGGL(hist_kernel, dim3(2048), dim3(256), 0, stream,
                           x, hist, n_points);
        hipLaunchKernelGGL(scan_kernel, dim3(1), dim3(256), 0, stream,
                           hist, offs);
        hipLaunchKernelGGL(scatter_kernel, dim3(2048), dim3(256), 0, stream,
                           x, offs, xs, n_points);
        hipLaunchKernelGGL(hash_encode_kernel<true>, dim3(blocks), dim3(256), 0,
                           stream, x, xs, tables, out, mask_out, n_points,
                           blocks_per_phase);
    } else {
        hipLaunchKernelGGL(hash_encode_kernel<false>, dim3(blocks), dim3(256), 0,
                           stream, x, (const f4*)nullptr, tables, out, mask_out,
                           n_points, blocks_per_phase);
    }
}

// Round 4
// 879.210 us; speedup vs baseline: 1.3101x; 1.3101x over previous
//
#include <hip/hip_runtime.h>
#include <stdint.h>

typedef float f2 __attribute__((ext_vector_type(2)));
typedef float f4 __attribute__((ext_vector_type(4)));

// res[l] = floor(16 * b^l), b = exp((ln512 - ln16)/15) in fp32.
__constant__ float c_res[16] = {16.f, 20.f, 25.f, 32.f, 40.f, 50.f, 64.f, 80.f,
                                101.f, 128.f, 161.f, 203.f, 256.f, 322.f, 406.f, 512.f};

#define HASH_MASK ((1u << 19) - 1u)
#define P1 2654435761u
#define P2 805459861u
#define PTS_PER_THREAD 4

// R0-R2 stuck at ~670us with WRITE_SIZE 528MB for a 128MB logical output: each
// 64B out-line (8 levels of one point) is partially dirtied by 8 blocks on 8
// DIFFERENT XCDs -> 16M 8B-dirty line evictions -> HBM partial-burst RMW.
// Fix: encode writes a level-major temp tmp[l][p] (f2): lane-coalesced, one
// writer-XCD per line, full-line dirty, L3-resident (128MB < 256MB L3). A
// transpose kernel then emits out[p][32] fully coalesced. Gather structure
// unchanged from R2 (XCD-pinned tables, x-paired 16B loads).
// WRITE_TMP=false is the direct-write fallback (exact R2 behavior).
template <bool WRITE_TMP>
__global__ __launch_bounds__(256, 4) void hash_encode_kernel(
    const float* __restrict__ x,
    const float* __restrict__ tables,
    f2* __restrict__ tmp,            // [nl][n_points] level-major
    float* __restrict__ out,         // only used when !WRITE_TMP
    float* __restrict__ mask_out,
    int n_points,
    int blocks_per_phase,
    int level_base_arg,              // used when !two_phase
    int two_phase)                   // 1: grid covers both phases
{
    int bid = blockIdx.x;
    int level_base = level_base_arg;
    if (two_phase) {
        level_base = 0;
        if (bid >= blocks_per_phase) { bid -= blocks_per_phase; level_base = 8; }
    }
    int level = (bid & 7) + level_base;
    // tmp row index: full mode stores all 16 levels; half mode stores 8.
    int trow = two_phase ? level : (bid & 7);
    int chunk = bid >> 3;

    float res  = c_res[level];
    float grid = 1.0f / res;
    const f2* __restrict__ tab =
        (const f2*)tables + ((size_t)level << 19);   // 2^19 float2 per level
    const f4* __restrict__ tab4 = (const f4*)tab;    // 2^18 float4 per level

    int pbase = chunk * (256 * PTS_PER_THREAD) + threadIdx.x;

    uint32_t idx[PTS_PER_THREAD][8];
    float wx[PTS_PER_THREAD], wy[PTS_PER_THREAD], wz[PTS_PER_THREAD];
    bool valid[PTS_PER_THREAD];
    bool bxodd[PTS_PER_THREAD];
    int pp[PTS_PER_THREAD];

    #pragma unroll
    for (int s = 0; s < PTS_PER_THREAD; ++s) {
        int p = pbase + s * 256;
        pp[s] = p;
        valid[s] = (p < n_points);
        int pc = valid[s] ? p : 0;

        // Plain loads: x is re-read once per level (16x); let L2/L3 cache it.
        // (Previous nontemporal hint streamed it -> ~192MB of HBM re-fetch.)
        float x0 = x[3 * (size_t)pc + 0];
        float x1 = x[3 * (size_t)pc + 1];
        float x2 = x[3 * (size_t)pc + 2];

        if (level == 0 && valid[s]) {
            bool keep = (x0 >= 0.f) & (x0 <= 1.f) &
                        (x1 >= 0.f) & (x1 <= 1.f) &
                        (x2 >= 0.f) & (x2 <= 1.f);
            __builtin_nontemporal_store(keep ? 1.0f : 0.0f, &mask_out[pc]);
        }

        x0 = fminf(fmaxf(x0, 0.f), 1.f);
        x1 = fminf(fmaxf(x1, 0.f), 1.f);
        x2 = fminf(fmaxf(x2, 0.f), 1.f);

        // Keep the exact fp32 sequence of the verified kernel (floor(x/grid)),
        // grid = 1/res: changing to x*res can flip buckets by 1 ulp.
        float b0 = floorf(x0 / grid);
        float b1 = floorf(x1 / grid);
        float b2 = floorf(x2 / grid);

        wx[s] = (x0 - b0 * grid) / grid;
        wy[s] = (x1 - b1 * grid) / grid;
        wz[s] = (x2 - b2 * grid) / grid;

        uint32_t bx = (uint32_t)b0;
        uint32_t by = (uint32_t)b1;
        uint32_t bz = (uint32_t)b2;

        bxodd[s] = (bx & 1u) != 0u;

        uint32_t hx0 = bx;        uint32_t hx1 = bx + 1u;
        uint32_t hy0 = by * P1;   uint32_t hy1 = hy0 + P1;
        uint32_t hz0 = bz * P2;   uint32_t hz1 = hz0 + P2;

        idx[s][0] = (hx0 ^ hy0 ^ hz0) & HASH_MASK;
        idx[s][1] = (hx0 ^ hy0 ^ hz1) & HASH_MASK;
        idx[s][2] = (hx0 ^ hy1 ^ hz0) & HASH_MASK;
        idx[s][3] = (hx0 ^ hy1 ^ hz1) & HASH_MASK;
        idx[s][4] = (hx1 ^ hy0 ^ hz0) & HASH_MASK;
        idx[s][5] = (hx1 ^ hy0 ^ hz1) & HASH_MASK;
        idx[s][6] = (hx1 ^ hy1 ^ hz0) & HASH_MASK;
        idx[s][7] = (hx1 ^ hy1 ^ hz1) & HASH_MASK;
    }

    // Issue all gathers before any consumption. Even-bx lanes: 4x16B paired
    // loads (idx[j] and idx[j]^1 == idx[j+4] share a float4). Odd-bx: 8x8B.
    f2 e[PTS_PER_THREAD][8];
    #pragma unroll
    for (int s = 0; s < PTS_PER_THREAD; ++s) {
        if (!bxodd[s]) {
            #pragma unroll
            for (int j = 0; j < 4; ++j) {
                uint32_t q = idx[s][j];
                f4 v = tab4[q >> 1];
                f2 lov = {v.x, v.y};
                f2 hiv = {v.z, v.w};
                bool hi = (q & 1u) != 0u;
                e[s][j]     = hi ? hiv : lov;   // entry q     (x = bx)
                e[s][j + 4] = hi ? lov : hiv;   // entry q ^ 1 (x = bx+1)
            }
        } else {
            #pragma unroll
            for (int c = 0; c < 8; ++c)
                e[s][c] = tab[idx[s][c]];
        }
    }

    #pragma unroll
    for (int s = 0; s < PTS_PER_THREAD; ++s) {
        float owx = 1.f - wx[s], owy = 1.f - wy[s], owz = 1.f - wz[s];

        f2 c00 = e[s][0] * owx + e[s][4] * wx[s];
        f2 c01 = e[s][1] * owx + e[s][5] * wx[s];
        f2 c10 = e[s][2] * owx + e[s][6] * wx[s];
        f2 c11 = e[s][3] * owx + e[s][7] * wx[s];

        f2 c0 = c00 * owy + c10 * wy[s];
        f2 c1 = c01 * owy + c11 * wy[s];

        f2 cv = c0 * owz + c1 * wz[s];

        if (valid[s]) {
            if constexpr (WRITE_TMP) {
                // Coalesced 8B/lane, single-writer line, L3-cacheable.
                tmp[(size_t)trow * n_points + pp[s]] = cv;
            } else {
                f2* dst = (f2*)(out + (size_t)pp[s] * 32) + level;
                __builtin_nontemporal_store(cv, dst);
            }
        }
    }
}

// tmp[l][p] (f2, l in [0,NL)) -> out[p][lb*2 .. lb*2+NL*2) coalesced.
template <int NL>
__global__ __launch_bounds__(256) void transpose_kernel(
    const f2* __restrict__ tmp,
    float* __restrict__ out,
    int n_points,
    int lb)
{
    int p = blockIdx.x * blockDim.x + threadIdx.x;
    if (p >= n_points) return;

    f2 v[NL];
    #pragma unroll
    for (int l = 0; l < NL; ++l)
        v[l] = tmp[(size_t)l * n_points + p];   // coalesced 8B/lane

    f4* dst = (f4*)(out + (size_t)p * 32 + lb * 2);
    #pragma unroll
    for (int k = 0; k < NL / 2; ++k) {
        f4 w = {v[2 * k].x, v[2 * k].y, v[2 * k + 1].x, v[2 * k + 1].y};
        __builtin_nontemporal_store(w, &dst[k]);
    }
}

extern "C" void kernel_launch(void* const* d_in, const int* in_sizes, int n_in,
                              void* d_out, int out_size, void* d_ws, size_t ws_size,
                              hipStream_t stream) {
    const float* x      = (const float*)d_in[0];
    const float* tables = (const float*)d_in[1];
    float* out = (float*)d_out;
    int n_points = in_sizes[0] / 3;
    float* mask_out = out + (size_t)n_points * 32;

    int chunks = (n_points + 256 * PTS_PER_THREAD - 1) / (256 * PTS_PER_THREAD);
    int blocks_per_phase = chunks * 8;
    int tblocks = (n_points + 255) / 256;

    size_t need_full = (size_t)n_points * 16 * sizeof(f2);  // 128MB @ 1M pts
    size_t need_half = (size_t)n_points * 8 * sizeof(f2);   //  64MB

    if (n_points > 0 && ws_size >= need_full) {
        f2* tmp = (f2*)d_ws;
        hipLaunchKernelGGL((hash_encode_kernel<true>), dim3(blocks_per_phase * 2),
                           dim3(256), 0, stream,
                           x, tables, tmp, out, mask_out, n_points,
                           blocks_per_phase, 0, 1);
        hipLaunchKernelGGL((transpose_kernel<16>), dim3(tblocks), dim3(256), 0,
                           stream, tmp, out, n_points, 0);
    } else if (n_points > 0 && ws_size >= need_half) {
        f2* tmp = (f2*)d_ws;
        // Phase A: levels 0-7 -> tmp rows 0-7 -> out floats [0,16)
        hipLaunchKernelGGL((hash_encode_kernel<true>), dim3(blocks_per_phase),
                           dim3(256), 0, stream,
                           x, tables, tmp, out, mask_out, n_points,
                           blocks_per_phase, 0, 0);
        hipLaunchKernelGGL((transpose_kernel<8>), dim3(tblocks), dim3(256), 0,
                           stream, tmp, out, n_points, 0);
        // Phase B: levels 8-15 -> tmp rows 0-7 -> out floats [16,32)
        hipLaunchKernelGGL((hash_encode_kernel<true>), dim3(blocks_per_phase),
                           dim3(256), 0, stream,
                           x, tables, tmp, out, mask_out, n_points,
                           blocks_per_phase, 8, 0);
        hipLaunchKernelGGL((transpose_kernel<8>), dim3(tblocks), dim3(256), 0,
                           stream, tmp, out, n_points, 8);
    } else {
        hipLaunchKernelGGL((hash_encode_kernel<false>), dim3(blocks_per_phase * 2),
                           dim3(256), 0, stream,
                           x, tables, (f2*)nullptr, out, mask_out, n_points,
                           blocks_per_phase, 0, 1);
    }
}

// Round 5
// 624.456 us; speedup vs baseline: 1.8445x; 1.4080x over previous
//
#include <hip/hip_runtime.h>
#include <stdint.h>

typedef float f2 __attribute__((ext_vector_type(2)));
typedef float f4 __attribute__((ext_vector_type(4)));

// res[l] = floor(16 * b^l), b = exp((ln512 - ln16)/15) in fp32.
__constant__ float c_res[16] = {16.f, 20.f, 25.f, 32.f, 40.f, 50.f, 64.f, 80.f,
                                101.f, 128.f, 161.f, 203.f, 256.f, 322.f, 406.f, 512.f};

#define HASH_MASK ((1u << 19) - 1u)
#define P1 2654435761u
#define P2 805459861u
#define PTS_PER_THREAD 4

// Encode (measured 442us in R4): XCD-pinned tables (blockIdx%8 == level%8),
// x-paired 16B gathers, writes a level-major temp tmp[l][p] (f2) --
// lane-coalesced, single-writer-XCD lines, full-line dirty -> WRITE_SIZE
// dropped 528MB -> 135MB and encode went 673 -> 442us.
// R4's transpose epilogue, however, ran at ~437us (~0.6 TB/s): its
// __builtin_nontemporal_store wrote 16B per lane at 128B lane stride -- NT
// defeats L2 write-merging, so every 64B line was partially dirtied at the MC
// (the same RMW disease the tmp buffer cured). R5 replaces it with an
// LDS-tiled transpose: coalesced reads, plain stores, 1KB contiguous per
// store instruction.
template <bool WRITE_TMP>
__global__ __launch_bounds__(256, 4) void hash_encode_kernel(
    const float* __restrict__ x,
    const float* __restrict__ tables,
    f2* __restrict__ tmp,            // [nl][n_points] level-major
    float* __restrict__ out,         // only used when !WRITE_TMP
    float* __restrict__ mask_out,
    int n_points,
    int blocks_per_phase,
    int level_base_arg,              // used when !two_phase
    int two_phase)                   // 1: grid covers both phases
{
    int bid = blockIdx.x;
    int level_base = level_base_arg;
    if (two_phase) {
        level_base = 0;
        if (bid >= blocks_per_phase) { bid -= blocks_per_phase; level_base = 8; }
    }
    int level = (bid & 7) + level_base;
    // tmp row index: full mode stores all 16 levels; half mode stores 8.
    int trow = two_phase ? level : (bid & 7);
    int chunk = bid >> 3;

    float res  = c_res[level];
    float grid = 1.0f / res;
    const f2* __restrict__ tab =
        (const f2*)tables + ((size_t)level << 19);   // 2^19 float2 per level
    const f4* __restrict__ tab4 = (const f4*)tab;    // 2^18 float4 per level

    int pbase = chunk * (256 * PTS_PER_THREAD) + threadIdx.x;

    uint32_t idx[PTS_PER_THREAD][8];
    float wx[PTS_PER_THREAD], wy[PTS_PER_THREAD], wz[PTS_PER_THREAD];
    bool valid[PTS_PER_THREAD];
    bool bxodd[PTS_PER_THREAD];
    int pp[PTS_PER_THREAD];

    #pragma unroll
    for (int s = 0; s < PTS_PER_THREAD; ++s) {
        int p = pbase + s * 256;
        pp[s] = p;
        valid[s] = (p < n_points);
        int pc = valid[s] ? p : 0;

        // Plain loads: x is re-read once per level (16x); let L2/L3 cache it.
        float x0 = x[3 * (size_t)pc + 0];
        float x1 = x[3 * (size_t)pc + 1];
        float x2 = x[3 * (size_t)pc + 2];

        if (level == 0 && valid[s]) {
            bool keep = (x0 >= 0.f) & (x0 <= 1.f) &
                        (x1 >= 0.f) & (x1 <= 1.f) &
                        (x2 >= 0.f) & (x2 <= 1.f);
            mask_out[pc] = keep ? 1.0f : 0.0f;
        }

        x0 = fminf(fmaxf(x0, 0.f), 1.f);
        x1 = fminf(fmaxf(x1, 0.f), 1.f);
        x2 = fminf(fmaxf(x2, 0.f), 1.f);

        // Keep the exact fp32 sequence of the verified kernel (floor(x/grid)),
        // grid = 1/res: changing to x*res can flip buckets by 1 ulp.
        float b0 = floorf(x0 / grid);
        float b1 = floorf(x1 / grid);
        float b2 = floorf(x2 / grid);

        wx[s] = (x0 - b0 * grid) / grid;
        wy[s] = (x1 - b1 * grid) / grid;
        wz[s] = (x2 - b2 * grid) / grid;

        uint32_t bx = (uint32_t)b0;
        uint32_t by = (uint32_t)b1;
        uint32_t bz = (uint32_t)b2;

        bxodd[s] = (bx & 1u) != 0u;

        uint32_t hx0 = bx;        uint32_t hx1 = bx + 1u;
        uint32_t hy0 = by * P1;   uint32_t hy1 = hy0 + P1;
        uint32_t hz0 = bz * P2;   uint32_t hz1 = hz0 + P2;

        idx[s][0] = (hx0 ^ hy0 ^ hz0) & HASH_MASK;
        idx[s][1] = (hx0 ^ hy0 ^ hz1) & HASH_MASK;
        idx[s][2] = (hx0 ^ hy1 ^ hz0) & HASH_MASK;
        idx[s][3] = (hx0 ^ hy1 ^ hz1) & HASH_MASK;
        idx[s][4] = (hx1 ^ hy0 ^ hz0) & HASH_MASK;
        idx[s][5] = (hx1 ^ hy0 ^ hz1) & HASH_MASK;
        idx[s][6] = (hx1 ^ hy1 ^ hz0) & HASH_MASK;
        idx[s][7] = (hx1 ^ hy1 ^ hz1) & HASH_MASK;
    }

    // Issue all gathers before any consumption. Even-bx lanes: 4x16B paired
    // loads (idx[j] and idx[j]^1 == idx[j+4] share a float4). Odd-bx: 8x8B.
    f2 e[PTS_PER_THREAD][8];
    #pragma unroll
    for (int s = 0; s < PTS_PER_THREAD; ++s) {
        if (!bxodd[s]) {
            #pragma unroll
            for (int j = 0; j < 4; ++j) {
                uint32_t q = idx[s][j];
                f4 v = tab4[q >> 1];
                f2 lov = {v.x, v.y};
                f2 hiv = {v.z, v.w};
                bool hi = (q & 1u) != 0u;
                e[s][j]     = hi ? hiv : lov;   // entry q     (x = bx)
                e[s][j + 4] = hi ? lov : hiv;   // entry q ^ 1 (x = bx+1)
            }
        } else {
            #pragma unroll
            for (int c = 0; c < 8; ++c)
                e[s][c] = tab[idx[s][c]];
        }
    }

    #pragma unroll
    for (int s = 0; s < PTS_PER_THREAD; ++s) {
        float owx = 1.f - wx[s], owy = 1.f - wy[s], owz = 1.f - wz[s];

        f2 c00 = e[s][0] * owx + e[s][4] * wx[s];
        f2 c01 = e[s][1] * owx + e[s][5] * wx[s];
        f2 c10 = e[s][2] * owx + e[s][6] * wx[s];
        f2 c11 = e[s][3] * owx + e[s][7] * wx[s];

        f2 c0 = c00 * owy + c10 * wy[s];
        f2 c1 = c01 * owy + c11 * wy[s];

        f2 cv = c0 * owz + c1 * wz[s];

        if (valid[s]) {
            if constexpr (WRITE_TMP) {
                // Coalesced 8B/lane, single-writer line, cache-merged.
                tmp[(size_t)trow * n_points + pp[s]] = cv;
            } else {
                f2* dst = (f2*)(out + (size_t)pp[s] * 32) + level;
                *dst = cv;
            }
        }
    }
}

// LDS-tiled transpose: tmp[l][p] (f2, l in [0,NL)) -> out[p][lb*2 ...).
// Stage 1: coalesced 8B/lane row reads into LDS (conflict-free writes).
// Stage 2: fully contiguous f4 stores -- consecutive lanes write consecutive
// 16B, so each store instruction covers 1KB of whole 64B lines (plain stores,
// L2-merged; NO nontemporal hint -- that was R4's 437us epilogue bug).
template <int NL>
__global__ __launch_bounds__(256) void transpose_kernel(
    const f2* __restrict__ tmp,
    float* __restrict__ out,
    int n_points,
    int lb)
{
    __shared__ f2 lds[NL][257];
    const int FP = NL / 2;                 // f4 per point in this phase
    int t = threadIdx.x;
    int p0 = blockIdx.x * 256;

    #pragma unroll
    for (int l = 0; l < NL; ++l) {
        int p = p0 + t;
        lds[l][t] = tmp[(size_t)l * n_points + (p < n_points ? p : 0)];
    }
    __syncthreads();

    f4* out4 = (f4*)out;
    #pragma unroll
    for (int i = 0; i < FP; ++i) {
        int g = i * 256 + t;
        int pidx = g / FP;                 // point within tile
        int k = g % FP;                    // f4 slot within point
        f2 a = lds[2 * k][pidx];
        f2 b = lds[2 * k + 1][pidx];
        f4 w = {a.x, a.y, b.x, b.y};
        int p = p0 + pidx;
        if (p < n_points)
            out4[(size_t)p * 8 + lb / 2 + k] = w;
    }
}

extern "C" void kernel_launch(void* const* d_in, const int* in_sizes, int n_in,
                              void* d_out, int out_size, void* d_ws, size_t ws_size,
                              hipStream_t stream) {
    const float* x      = (const float*)d_in[0];
    const float* tables = (const float*)d_in[1];
    float* out = (float*)d_out;
    int n_points = in_sizes[0] / 3;
    float* mask_out = out + (size_t)n_points * 32;

    int chunks = (n_points + 256 * PTS_PER_THREAD - 1) / (256 * PTS_PER_THREAD);
    int blocks_per_phase = chunks * 8;
    int tblocks = (n_points + 255) / 256;

    size_t need_full = (size_t)n_points * 16 * sizeof(f2);  // 128MB @ 1M pts
    size_t need_half = (size_t)n_points * 8 * sizeof(f2);   //  64MB

    if (n_points > 0 && ws_size >= need_full) {
        f2* tmp = (f2*)d_ws;
        hipLaunchKernelGGL((hash_encode_kernel<true>), dim3(blocks_per_phase * 2),
                           dim3(256), 0, stream,
                           x, tables, tmp, out, mask_out, n_points,
                           blocks_per_phase, 0, 1);
        hipLaunchKernelGGL((transpose_kernel<16>), dim3(tblocks), dim3(256), 0,
                           stream, tmp, out, n_points, 0);
    } else if (n_points > 0 && ws_size >= need_half) {
        f2* tmp = (f2*)d_ws;
        // Phase A: levels 0-7 -> tmp rows 0-7 -> out floats [0,16)
        hipLaunchKernelGGL((hash_encode_kernel<true>), dim3(blocks_per_phase),
                           dim3(256), 0, stream,
                           x, tables, tmp, out, mask_out, n_points,
                           blocks_per_phase, 0, 0);
        hipLaunchKernelGGL((transpose_kernel<8>), dim3(tblocks), dim3(256), 0,
                           stream, tmp, out, n_points, 0);
        // Phase B: levels 8-15 -> tmp rows 0-7 -> out floats [16,32)
        hipLaunchKernelGGL((hash_encode_kernel<true>), dim3(blocks_per_phase),
                           dim3(256), 0, stream,
                           x, tables, tmp, out, mask_out, n_points,
                           blocks_per_phase, 8, 0);
        hipLaunchKernelGGL((transpose_kernel<8>), dim3(tblocks), dim3(256), 0,
                           stream, tmp, out, n_points, 8);
    } else {
        hipLaunchKernelGGL((hash_encode_kernel<false>), dim3(blocks_per_phase * 2),
                           dim3(256), 0, stream,
                           x, tables, (f2*)nullptr, out, mask_out, n_points,
                           blocks_per_phase, 0, 1);
    }
}